// Round 11
// baseline (117.529 us; speedup 1.0000x reference)
//
#include <hip/hip_runtime.h>

#define BATCH   8
#define CH      64
#define H       128
#define W       128
#define HW      (H * W)            // 16384
#define SPW     132                // padded row stride (floats), 16B-multiple
#define SPH     130
#define SPPLANE (SPH * SPW)        // 17160 floats = 68640 B (16B-multiple)

__device__ __forceinline__ float sigmoidf_(float v) {
    return 1.0f / (1.0f + __expf(-v));
}

// wave-uniform float -> SGPR
__device__ __forceinline__ float uni_(float v) {
    return __int_as_float(__builtin_amdgcn_readfirstlane(__float_as_int(v)));
}

// median-of-9 (McGuire ShaderX6 network); d[] is clobbered, result returned
__device__ __forceinline__ float med9_(float d[9]) {
    #define S2(a,bb) { float t_ = d[a]; d[a] = fminf(d[a], d[bb]); d[bb] = fmaxf(t_, d[bb]); }
    S2(0,3) S2(1,4) S2(2,5) S2(0,1) S2(0,2) S2(4,5) S2(3,5)
    S2(1,2) S2(3,4) S2(1,3) S2(1,6) S2(4,6) S2(2,6)
    S2(2,3) S2(4,7) S2(2,4) S2(3,7)
    S2(4,8) S2(3,8) S2(3,4)
    #undef S2
    return d[4];
}

// Kernel 0: sp[b][c][pr][pc] = sigmoid(x) with a 1-px zero border (pad AFTER
// sigmoid). Thread t handles pixel cols j and j+64 of one row (both stores
// perfectly coalesced), border threads also zero the pad edges. No memset.
__global__ __launch_bounds__(256) void sig_pad_kernel(
    const float* __restrict__ x, float* __restrict__ sp)
{
    const int t  = blockIdx.x * 256 + threadIdx.x;   // [0, B*CH*H*64)
    const int j  = t & 63;
    const int r  = (t >> 6) & 127;
    const int bc = t >> 13;                          // b*CH + c

    const float* xp  = x  + (size_t)bc * HW + (size_t)r * W;
    float*       pl  = sp + (size_t)bc * SPPLANE;
    float*       row = pl + (size_t)(r + 1) * SPW;

    row[j + 1]  = sigmoidf_(xp[j]);
    row[j + 65] = sigmoidf_(xp[j + 64]);

    // zero borders (ws is re-poisoned before every launch, must rewrite)
    if (j == 0)  row[0]   = 0.0f;                    // left pad, this row
    if (j == 63) row[129] = 0.0f;                    // right pad, this row
    if (r == 0) {                                    // top pad row
        pl[j] = 0.0f; pl[j + 64] = 0.0f;
        if (j == 0) { pl[128] = 0.0f; pl[129] = 0.0f; }
    }
    if (r == 127) {                                  // bottom pad row
        float* bp = pl + (size_t)129 * SPW;
        bp[j] = 0.0f; bp[j + 64] = 0.0f;
        if (j == 0) { bp[128] = 0.0f; bp[129] = 0.0f; }
    }
}

// per-pixel, per-channel contribution. UNIF = all bias terms equal (then the
// median network runs on m[k]=max(wk,pk) and adds b0 once).
template <bool UNIF>
__device__ __forceinline__ float px_term(
    const float* __restrict__ q,      // &sp[plane][r][j] (padded window origin)
    const float* __restrict__ wk, const float* __restrict__ bk,
    float wc, float wm, float SB, float b0)
{
    const float p0 = q[0],           p1 = q[1],           p2 = q[2];
    const float p3 = q[SPW],         p4 = q[SPW + 1],     p5 = q[SPW + 2];
    const float p6 = q[2 * SPW],     p7 = q[2 * SPW + 1], p8 = q[2 * SPW + 2];

    float m[9];
    m[0] = fmaxf(wk[0], p0); m[1] = fmaxf(wk[1], p1); m[2] = fmaxf(wk[2], p2);
    m[3] = fmaxf(wk[3], p3); m[4] = fmaxf(wk[4], p4); m[5] = fmaxf(wk[5], p5);
    m[6] = fmaxf(wk[6], p6); m[7] = fmaxf(wk[7], p7); m[8] = fmaxf(wk[8], p8);
    const float sum_m = ((m[0] + m[1]) + (m[2] + m[3]))
                      + ((m[5] + m[6]) + (m[7] + m[8])) + m[4];

    float med;
    if (UNIF) {
        med = med9_(m) + b0;              // m[] clobbered after sum_m - fine
    } else {
        float d[9];
        #pragma unroll
        for (int k = 0; k < 9; ++k) d[k] = m[k] + bk[k];
        med = med9_(d);
    }

    const float sumD = sum_m + SB;
    return wc * p4 + wm * med - sumD - sumD * (1.0f / 9.0f);
}

// Kernel 1: block = 64 pixels (half image row) x 4 channel-groups of 16.
// Each thread: 16 channels x (9 dword loads from sp + max/median network),
// LDS reduce across the 4 groups (one barrier), then each wave broadcasts
// the pixel sum to its 16 output planes with NT coalesced stores.
__global__ __launch_bounds__(256) void reduce_bcast_kernel(
    const float* __restrict__ sp,
    const float* __restrict__ weight,
    const float* __restrict__ bias,
    const float* __restrict__ wcp,
    const float* __restrict__ wmp,
    float* __restrict__ out)
{
    __shared__ float red[4][64];

    const int tid = threadIdx.x;
    const int px  = tid & 63;
    const int g   = tid >> 6;                 // channel group 0..3
    const int blk = blockIdx.x;               // [0, B*H*2)
    const int hh  = blk & 1;
    const int r   = (blk >> 1) & 127;
    const int b   = blk >> 8;
    const int j   = hh * 64 + px;

    float wk[9], bk[9];
    #pragma unroll
    for (int k = 0; k < 9; ++k) {
        wk[k] = uni_(sigmoidf_(weight[k]));
        bk[k] = uni_(sigmoidf_(bias[k]));
    }
    const float wc = uni_(wcp[0]);
    const float wm = uni_(wmp[0]);
    const float SB = ((bk[0] + bk[1]) + (bk[2] + bk[3]))
                   + ((bk[5] + bk[6]) + (bk[7] + bk[8])) + bk[4];
    const float b0 = bk[0];
    const bool unif = (bk[0] == bk[1]) & (bk[1] == bk[2]) & (bk[2] == bk[3])
                    & (bk[3] == bk[4]) & (bk[4] == bk[5]) & (bk[5] == bk[6])
                    & (bk[6] == bk[7]) & (bk[7] == bk[8]);

    // padded window origin for pixel (r, j): padded rows r..r+2, cols j..j+2
    const float* base = sp + ((size_t)b * CH + g * 16) * SPPLANE
                           + (size_t)r * SPW + j;

    float acc = 0.0f;
    if (unif) {
        #pragma unroll 2
        for (int c = 0; c < 16; ++c)
            acc += px_term<true >(base + (size_t)c * SPPLANE, wk, bk, wc, wm, SB, b0);
    } else {
        #pragma unroll 2
        for (int c = 0; c < 16; ++c)
            acc += px_term<false>(base + (size_t)c * SPPLANE, wk, bk, wc, wm, SB, b0);
    }

    red[g][px] = acc;
    __syncthreads();
    const float s = (red[0][px] + red[1][px]) + (red[2][px] + red[3][px]);

    float* op = out + ((size_t)b * CH + g * 16) * HW + (size_t)r * W + j;
    #pragma unroll
    for (int co = 0; co < 16; ++co)
        __builtin_nontemporal_store(s, op + (size_t)co * HW);
}

extern "C" void kernel_launch(void* const* d_in, const int* in_sizes, int n_in,
                              void* d_out, int out_size, void* d_ws, size_t ws_size,
                              hipStream_t stream) {
    const float* x      = (const float*)d_in[0];
    const float* weight = (const float*)d_in[1];
    const float* bias   = (const float*)d_in[2];
    const float* wcp    = (const float*)d_in[3];
    const float* wmp    = (const float*)d_in[4];
    float* out = (float*)d_out;
    float* sp  = (float*)d_ws;    // 8*64*17160*4 B = 35.1 MB used

    const int n0 = BATCH * CH * H * 64;              // 4,194,304 threads
    sig_pad_kernel<<<n0 / 256, 256, 0, stream>>>(x, sp);

    const int n1 = BATCH * H * 2;                    // 2048 blocks
    reduce_bcast_kernel<<<n1, 256, 0, stream>>>(sp, weight, bias, wcp, wmp, out);
}